// Round 1
// baseline (16.749 us; speedup 1.0000x reference)
//
#include <hip/hip_runtime.h>
#include <math.h>

constexpr int SEQ = 8192;
constexpr int HID = 16;
constexpr int BLK = 128;            // threads per block (2 waves)
constexpr int NBLK = SEQ / BLK;     // 64 blocks
constexpr int WS_STRIDE = 48;       // per-block partial: 16 A + 16 B + 1 Vtot (padded)

__device__ __forceinline__ void load_row(const float* __restrict__ x, int r, float* f) {
    const float4* p = (const float4*)(x + (size_t)r * HID);
    float4 a = p[0], b = p[1], c = p[2], d = p[3];
    f[0]=a.x; f[1]=a.y; f[2]=a.z;  f[3]=a.w;
    f[4]=b.x; f[5]=b.y; f[6]=b.z;  f[7]=b.w;
    f[8]=c.x; f[9]=c.y; f[10]=c.z; f[11]=c.w;
    f[12]=d.x; f[13]=d.y; f[14]=d.z; f[15]=d.w;
}

__global__ __launch_bounds__(BLK) void satformer_main(
    const float* __restrict__ x,
    const float* __restrict__ Wq, const float* __restrict__ bq,
    const float* __restrict__ Wk, const float* __restrict__ bk,
    const float* __restrict__ Wv, const float* __restrict__ bv,
    const int* __restrict__ heads_p,
    float* __restrict__ part)
{
    __shared__ float sWq[256];
    __shared__ float sWk[256];
    __shared__ float swv[16];     // column sums of Wv: swv[h] = sum_d Wv[d][h]
    __shared__ float sbq[16];
    __shared__ float sbk[16];
    __shared__ float sbv;         // sum of bv
    __shared__ float sK[BLK + 2][17];   // K rows r0-1 .. r0+BLK, padded (+1) -> 2-way bank alias only
    __shared__ float sVr[BLK + 2];      // V row-sums for same rows
    __shared__ float redA[2][16];
    __shared__ float redB[2][16];
    __shared__ float redV[2];

    const int tid = threadIdx.x;
    const int r0  = blockIdx.x * BLK;

    for (int i = tid; i < 256; i += BLK) { sWq[i] = Wq[i]; sWk[i] = Wk[i]; }
    if (tid < 16) {
        float acc = 0.f;
        #pragma unroll
        for (int d = 0; d < 16; ++d) acc += Wv[d * 16 + tid];
        swv[tid] = acc;
        sbq[tid] = bq[tid];
        sbk[tid] = bk[tid];
    }
    if (tid == BLK - 1) {
        float acc = 0.f;
        #pragma unroll
        for (int d = 0; d < 16; ++d) acc += bv[d];
        sbv = acc;
    }
    __syncthreads();

    // scaling = (HID/heads)^-0.5 ; heads=4 -> exactly 0.5
    const float scaling = rsqrtf((float)(HID / heads_p[0]));

    const int s = r0 + tid;
    float xs[16];
    load_row(x, s, xs);

    // Own row's K vector and V row-sum into LDS
    #pragma unroll
    for (int d = 0; d < 16; ++d) {
        float acc = sbk[d];
        #pragma unroll
        for (int h = 0; h < 16; ++h) acc += xs[h] * sWk[d * 16 + h];
        sK[tid + 1][d] = acc;
    }
    {
        float acc = sbv;
        #pragma unroll
        for (int h = 0; h < 16; ++h) acc += xs[h] * swv[h];
        sVr[tid + 1] = acc;
    }

    // Boundary rows (r0-1 and r0+BLK) handled by edge threads
    auto fill = [&](int row, int slot) {
        float xr[16];
        load_row(x, row, xr);
        #pragma unroll
        for (int d = 0; d < 16; ++d) {
            float acc = sbk[d];
            #pragma unroll
            for (int h = 0; h < 16; ++h) acc += xr[h] * sWk[d * 16 + h];
            sK[slot][d] = acc;
        }
        float acc = sbv;
        #pragma unroll
        for (int h = 0; h < 16; ++h) acc += xr[h] * swv[h];
        sVr[slot] = acc;
    };
    if (tid == 0 && r0 > 0)                 fill(r0 - 1, 0);
    if (tid == BLK - 1 && r0 + BLK < SEQ)   fill(r0 + BLK, BLK + 1);

    // Q for own row (registers)
    float q[16];
    #pragma unroll
    for (int d = 0; d < 16; ++d) {
        float acc = sbq[d];
        #pragma unroll
        for (int h = 0; h < 16; ++h) acc += xs[h] * sWq[d * 16 + h];
        q[d] = acc;
    }
    __syncthreads();

    // Band: j in {s-1, s, s+1} ∩ [0, SEQ)
    float denom = 0.f, num = 0.f;
    int nb = 0;
    #pragma unroll
    for (int off = -1; off <= 1; ++off) {
        int j = s + off;
        if (j < 0 || j >= SEQ) continue;
        int li = tid + 1 + off;
        float sc = 0.f;
        #pragma unroll
        for (int d = 0; d < 16; ++d) sc += q[d] * sK[li][d];
        sc *= scaling;
        float e = expf(sc);
        denom += e;
        num   += (e - 1.f) * sVr[li];
        ++nb;
    }
    denom += (float)(SEQ - nb);   // the (S-nb) off-band exp(0)=1 terms

    float a  = num / denom;       // per-row A contribution
    float b  = 1.f / denom;       // per-row B contribution
    float v  = sVr[tid + 1];      // per-row Vtot contribution

    // Bucket c = s & 15 == tid & 15. xor-16/32 folds preserve the bucket.
    float av = a, bb = b, vv = v;
    av += __shfl_xor(av, 16); av += __shfl_xor(av, 32);
    bb += __shfl_xor(bb, 16); bb += __shfl_xor(bb, 32);
    #pragma unroll
    for (int m = 1; m <= 32; m <<= 1) vv += __shfl_xor(vv, m);

    const int wave = tid >> 6;
    const int lane = tid & 63;
    if (lane < 16) { redA[wave][lane] = av; redB[wave][lane] = bb; }
    if (lane == 0) redV[wave] = vv;
    __syncthreads();

    if (tid < 16) {
        part[blockIdx.x * WS_STRIDE + tid]      = redA[0][tid] + redA[1][tid];
        part[blockIdx.x * WS_STRIDE + 16 + tid] = redB[0][tid] + redB[1][tid];
    }
    if (tid == 16) {
        part[blockIdx.x * WS_STRIDE + 32] = redV[0] + redV[1];
    }
}

__global__ __launch_bounds__(128) void satformer_finish(
    const float* __restrict__ part, float* __restrict__ out)
{
    const int j = threadIdx.x;       // 0..127
    const int c = j >> 3;            // output bin j reads pooled column j/8
    float A = 0.f, B = 0.f, V = 0.f;
    for (int k = 0; k < NBLK; ++k) {
        A += part[k * WS_STRIDE + c];
        B += part[k * WS_STRIDE + 16 + c];
        V += part[k * WS_STRIDE + 32];
    }
    out[j] = (A + V * B) / (float)SEQ;
}

extern "C" void kernel_launch(void* const* d_in, const int* in_sizes, int n_in,
                              void* d_out, int out_size, void* d_ws, size_t ws_size,
                              hipStream_t stream) {
    const float* x     = (const float*)d_in[0];
    const float* Wq    = (const float*)d_in[1];
    const float* bq    = (const float*)d_in[2];
    const float* Wk    = (const float*)d_in[3];
    const float* bk    = (const float*)d_in[4];
    const float* Wv    = (const float*)d_in[5];
    const float* bv    = (const float*)d_in[6];
    const int*   heads = (const int*)d_in[7];
    float* part = (float*)d_ws;          // NBLK * WS_STRIDE * 4 = 12 KiB
    float* out  = (float*)d_out;

    hipLaunchKernelGGL(satformer_main, dim3(NBLK), dim3(BLK), 0, stream,
                       x, Wq, bq, Wk, bk, Wv, bv, heads, part);
    hipLaunchKernelGGL(satformer_finish, dim3(1), dim3(128), 0, stream,
                       part, out);
}